// Round 1
// baseline (1043.683 us; speedup 1.0000x reference)
//
#include <hip/hip_runtime.h>

typedef _Float16 f16x8 __attribute__((ext_vector_type(8)));
typedef float    f32x4 __attribute__((ext_vector_type(4)));

// Problem constants
#define SEQL 1024
#define EMB  1024
#define NH   16
#define HD   64
#define BATCH 8

// ---------------------------------------------------------------------------
// fp32 -> fp16 conversion, 8 elements per thread
// ---------------------------------------------------------------------------
__global__ __launch_bounds__(256) void k_cvt_f32_f16(const float* __restrict__ in,
                                                     _Float16* __restrict__ out,
                                                     int n8) {
  int i = blockIdx.x * 256 + threadIdx.x;
  if (i >= n8) return;
  const float4* p = (const float4*)in;
  float4 a = p[2 * i], b = p[2 * i + 1];
  f16x8 o;
  o[0] = (_Float16)a.x; o[1] = (_Float16)a.y; o[2] = (_Float16)a.z; o[3] = (_Float16)a.w;
  o[4] = (_Float16)b.x; o[5] = (_Float16)b.y; o[6] = (_Float16)b.z; o[7] = (_Float16)b.w;
  ((f16x8*)out)[i] = o;
}

// ---------------------------------------------------------------------------
// NT GEMM: C[M,N] = A[M,K] * B[N,K]^T + bias[N]
// A,B fp16 row-major (K contiguous). 128x128 tile, BK=32, 4 waves (2x2 of 64x64).
// OUT_F16: 1 -> fp16 output, 0 -> fp32 output.
// ---------------------------------------------------------------------------
template <int OUT_F16>
__global__ __launch_bounds__(256) void k_gemm_nt(const _Float16* __restrict__ A,
                                                 const _Float16* __restrict__ B,
                                                 const float* __restrict__ bias,
                                                 void* __restrict__ Cv,
                                                 int M, int N, int K) {
  __shared__ __align__(16) _Float16 As[128 * 32];
  __shared__ __align__(16) _Float16 Bs[128 * 32];
  const int nb = N >> 7;
  const int bm = (int)blockIdx.x / nb, bn = (int)blockIdx.x % nb;
  const int m0 = bm << 7, n0 = bn << 7;
  const int tid = threadIdx.x;
  const int wave = tid >> 6, lane = tid & 63, quad = lane >> 4, l16 = lane & 15;
  const int wm = (wave & 1) << 6, wn = (wave >> 1) << 6;

  f32x4 acc[4][4] = {};

  const int c0 = tid, c1 = tid + 256;
  const int row0 = c0 >> 2, ko0 = (c0 & 3) << 3;
  const int row1 = c1 >> 2, ko1 = (c1 & 3) << 3;

  for (int k0 = 0; k0 < K; k0 += 32) {
    __syncthreads();
    ((uint4*)As)[c0] = *(const uint4*)(A + (size_t)(m0 + row0) * K + k0 + ko0);
    ((uint4*)As)[c1] = *(const uint4*)(A + (size_t)(m0 + row1) * K + k0 + ko1);
    ((uint4*)Bs)[c0] = *(const uint4*)(B + (size_t)(n0 + row0) * K + k0 + ko0);
    ((uint4*)Bs)[c1] = *(const uint4*)(B + (size_t)(n0 + row1) * K + k0 + ko1);
    __syncthreads();

    f16x8 af[4], bf[4];
#pragma unroll
    for (int i = 0; i < 4; ++i)
      af[i] = *(const f16x8*)(As + ((wm + (i << 4) + l16) << 5) + (quad << 3));
#pragma unroll
    for (int i = 0; i < 4; ++i)
      bf[i] = *(const f16x8*)(Bs + ((wn + (i << 4) + l16) << 5) + (quad << 3));
#pragma unroll
    for (int i = 0; i < 4; ++i)
#pragma unroll
      for (int j = 0; j < 4; ++j)
        acc[i][j] = __builtin_amdgcn_mfma_f32_16x16x32_f16(af[i], bf[j], acc[i][j], 0, 0, 0);
  }

#pragma unroll
  for (int j = 0; j < 4; ++j) {
    int col = n0 + wn + (j << 4) + l16;
    float bb = bias[col];
#pragma unroll
    for (int i = 0; i < 4; ++i) {
      int rowb = m0 + wm + (i << 4) + (quad << 2);
#pragma unroll
      for (int r = 0; r < 4; ++r) {
        float v = acc[i][j][r] + bb;
        if (OUT_F16)
          ((_Float16*)Cv)[(size_t)(rowb + r) * N + col] = (_Float16)v;
        else
          ((float*)Cv)[(size_t)(rowb + r) * N + col] = v;
      }
    }
  }
}

// ---------------------------------------------------------------------------
// V (b, s, h*64+d) fp16  ->  Vt (b, h, d, s) fp16
// lane-consecutive d for coalesced reads; 16B contiguous store per thread.
// ---------------------------------------------------------------------------
__global__ __launch_bounds__(256) void k_transpose_v(const _Float16* __restrict__ V,
                                                     _Float16* __restrict__ Vt) {
  int tid = blockIdx.x * 256 + threadIdx.x;  // 2^20 threads
  int d = tid & 63;
  int s0 = ((tid >> 6) & 127) << 3;
  int h = (tid >> 13) & 15;
  int b = tid >> 17;
  const _Float16* src = V + ((size_t)(b * SEQL + s0)) * EMB + h * HD + d;
  f16x8 t;
#pragma unroll
  for (int j = 0; j < 8; ++j) t[j] = src[(size_t)j * EMB];
  *(f16x8*)(Vt + ((size_t)((b * NH + h) * HD + d)) * SEQL + s0) = t;
}

// ---------------------------------------------------------------------------
// Scores + softmax, fused. Block = (qt, h, b): 16 Q rows x 1024 K cols.
// 4 waves, each covers 256 K cols; full score block kept in registers
// (p[16][4] per lane). Cross-l16 reduce by shuffles, cross-wave via tiny LDS.
// Writes normalized aw (fp32) once.
// ---------------------------------------------------------------------------
__global__ __launch_bounds__(256) void k_scores_softmax(const _Float16* __restrict__ Q,
                                                        const _Float16* __restrict__ Kmat,
                                                        const int* __restrict__ mask,
                                                        float* __restrict__ aw) {
  const int qt = blockIdx.x, h = blockIdx.y, b = blockIdx.z;
  const int tid = threadIdx.x;
  const int wave = tid >> 6, lane = tid & 63, quad = lane >> 4, l16 = lane & 15;

  const _Float16* Qbase = Q + ((size_t)(b * SEQL + qt * 16 + l16)) * EMB + h * HD + quad * 8;
  f16x8 qf0 = *(const f16x8*)(Qbase);
  f16x8 qf1 = *(const f16x8*)(Qbase + 32);

  float p[16][4];
  float mr[4], lr[4];
#pragma unroll
  for (int r = 0; r < 4; ++r) mr[r] = -3.0e38f;

  const int* mrow = mask + b * SEQL;

#pragma unroll
  for (int ct = 0; ct < 16; ++ct) {
    int col = wave * 256 + ct * 16 + l16;
    const _Float16* Kb = Kmat + ((size_t)(b * SEQL + col)) * EMB + h * HD + quad * 8;
    f16x8 kf0 = *(const f16x8*)(Kb);
    f16x8 kf1 = *(const f16x8*)(Kb + 32);
    f32x4 acc = {};
    acc = __builtin_amdgcn_mfma_f32_16x16x32_f16(qf0, kf0, acc, 0, 0, 0);
    acc = __builtin_amdgcn_mfma_f32_16x16x32_f16(qf1, kf1, acc, 0, 0, 0);
    bool mk = (mrow[col] == 0);
#pragma unroll
    for (int r = 0; r < 4; ++r) {
      float s = acc[r] * 0.125f;          // 1/sqrt(64)
      s = fminf(fmaxf(s, -50.f), 50.f);   // clip BEFORE mask (matches ref)
      if (mk) s = -1.0e9f;
      p[ct][r] = s;
      mr[r] = fmaxf(mr[r], s);
    }
  }

  // wave-level row max (reduce over 16 lanes sharing a quad)
#pragma unroll
  for (int r = 0; r < 4; ++r) {
    float m = mr[r];
    m = fmaxf(m, __shfl_xor(m, 1, 16));
    m = fmaxf(m, __shfl_xor(m, 2, 16));
    m = fmaxf(m, __shfl_xor(m, 4, 16));
    m = fmaxf(m, __shfl_xor(m, 8, 16));
    mr[r] = m;
  }

  // exp + wave-level row sum; p becomes exp(s - m_wave)
#pragma unroll
  for (int r = 0; r < 4; ++r) lr[r] = 0.f;
#pragma unroll
  for (int ct = 0; ct < 16; ++ct) {
#pragma unroll
    for (int r = 0; r < 4; ++r) {
      float e = __expf(p[ct][r] - mr[r]);
      p[ct][r] = e;
      lr[r] += e;
    }
  }
#pragma unroll
  for (int r = 0; r < 4; ++r) {
    float l = lr[r];
    l += __shfl_xor(l, 1, 16);
    l += __shfl_xor(l, 2, 16);
    l += __shfl_xor(l, 4, 16);
    l += __shfl_xor(l, 8, 16);
    lr[r] = l;
  }

  // cross-wave combine
  __shared__ float sm[4][16], sl[4][16];
  if (l16 == 0) {
#pragma unroll
    for (int r = 0; r < 4; ++r) {
      sm[wave][quad * 4 + r] = mr[r];
      sl[wave][quad * 4 + r] = lr[r];
    }
  }
  __syncthreads();

  float f[4];
#pragma unroll
  for (int r = 0; r < 4; ++r) {
    int row = quad * 4 + r;
    float M = fmaxf(fmaxf(sm[0][row], sm[1][row]), fmaxf(sm[2][row], sm[3][row]));
    float L = sl[0][row] * __expf(sm[0][row] - M) + sl[1][row] * __expf(sm[1][row] - M) +
              sl[2][row] * __expf(sm[2][row] - M) + sl[3][row] * __expf(sm[3][row] - M);
    f[r] = __expf(mr[r] - M) / L;
  }

  float* awb = aw + (((size_t)(b * NH + h)) * SEQL + qt * 16) * SEQL;
#pragma unroll
  for (int ct = 0; ct < 16; ++ct) {
    int col = wave * 256 + ct * 16 + l16;
#pragma unroll
    for (int r = 0; r < 4; ++r) {
      awb[(size_t)(quad * 4 + r) * SEQL + col] = p[ct][r] * f[r];
    }
  }
}

// ---------------------------------------------------------------------------
// PV: attended[b, s, h*64+d] (fp16) = sum_k aw[b,h,s,k] * V[b,k,h*64+d]
// Vt layout (b,h,d,s) makes B-fragments contiguous. Block = 64 s-rows.
// ---------------------------------------------------------------------------
__global__ __launch_bounds__(256) void k_attn_pv(const float* __restrict__ aw,
                                                 const _Float16* __restrict__ Vt,
                                                 _Float16* __restrict__ att) {
  const int mt = blockIdx.x;  // 16 tiles of 64 rows
  const int h = blockIdx.y, b = blockIdx.z;
  const int tid = threadIdx.x;
  const int wave = tid >> 6, lane = tid & 63, quad = lane >> 4, l16 = lane & 15;
  const int m0 = mt * 64 + wave * 16;

  const float* awrow = aw + (((size_t)(b * NH + h)) * SEQL + m0 + l16) * SEQL;
  const _Float16* vtb = Vt + ((size_t)(b * NH + h)) * HD * SEQL;

  f32x4 acc[4] = {};

  for (int k0 = 0; k0 < SEQL; k0 += 32) {
    float4 a0 = *(const float4*)(awrow + k0 + quad * 8);
    float4 a1 = *(const float4*)(awrow + k0 + quad * 8 + 4);
    f16x8 af;
    af[0] = (_Float16)a0.x; af[1] = (_Float16)a0.y; af[2] = (_Float16)a0.z; af[3] = (_Float16)a0.w;
    af[4] = (_Float16)a1.x; af[5] = (_Float16)a1.y; af[6] = (_Float16)a1.z; af[7] = (_Float16)a1.w;
#pragma unroll
    for (int nt = 0; nt < 4; ++nt) {
      f16x8 bf = *(const f16x8*)(vtb + (size_t)(nt * 16 + l16) * SEQL + k0 + quad * 8);
      acc[nt] = __builtin_amdgcn_mfma_f32_16x16x32_f16(af, bf, acc[nt], 0, 0, 0);
    }
  }

#pragma unroll
  for (int nt = 0; nt < 4; ++nt) {
    int d = nt * 16 + l16;
#pragma unroll
    for (int r = 0; r < 4; ++r) {
      int srow = m0 + quad * 4 + r;
      att[((size_t)(b * SEQL + srow)) * EMB + h * HD + d] = (_Float16)acc[nt][r];
    }
  }
}

// ---------------------------------------------------------------------------
// launch
// ---------------------------------------------------------------------------
extern "C" void kernel_launch(void* const* d_in, const int* in_sizes, int n_in,
                              void* d_out, int out_size, void* d_ws, size_t ws_size,
                              hipStream_t stream) {
  const float* x  = (const float*)d_in[0];
  const int* mask = (const int*)d_in[1];
  const float* Wq = (const float*)d_in[2];
  const float* bq = (const float*)d_in[3];
  const float* Wk = (const float*)d_in[4];
  const float* bk = (const float*)d_in[5];
  const float* Wv = (const float*)d_in[6];
  const float* bv = (const float*)d_in[7];
  const float* Wo = (const float*)d_in[8];
  const float* bo = (const float*)d_in[9];

  float* out = (float*)d_out;
  float* aw = out + (size_t)BATCH * SEQL * EMB;  // 8,388,608

  char* ws = (char*)d_ws;
  _Float16* x16  = (_Float16*)(ws);                        // 16 MB
  _Float16* Wq16 = (_Float16*)(ws + ((size_t)16 << 20));   // 2 MB
  _Float16* Wk16 = (_Float16*)(ws + ((size_t)18 << 20));
  _Float16* Wv16 = (_Float16*)(ws + ((size_t)20 << 20));
  _Float16* Wo16 = (_Float16*)(ws + ((size_t)22 << 20));
  _Float16* Q16  = (_Float16*)(ws + ((size_t)24 << 20));   // 16 MB
  _Float16* K16  = (_Float16*)(ws + ((size_t)40 << 20));   // 16 MB
  _Float16* V16  = (_Float16*)(ws + ((size_t)56 << 20));   // 16 MB  (total 72 MB)
  _Float16* Vt16  = x16;  // alias: x dead after V projection
  _Float16* att16 = Q16;  // alias: Q dead after scores kernel

  const int M = BATCH * SEQL, N = EMB, K = EMB;

  k_cvt_f32_f16<<<4096, 256, 0, stream>>>(x, x16, (M * EMB) / 8);
  k_cvt_f32_f16<<<512, 256, 0, stream>>>(Wq, Wq16, (EMB * EMB) / 8);
  k_cvt_f32_f16<<<512, 256, 0, stream>>>(Wk, Wk16, (EMB * EMB) / 8);
  k_cvt_f32_f16<<<512, 256, 0, stream>>>(Wv, Wv16, (EMB * EMB) / 8);
  k_cvt_f32_f16<<<512, 256, 0, stream>>>(Wo, Wo16, (EMB * EMB) / 8);

  k_gemm_nt<1><<<(M / 128) * (N / 128), 256, 0, stream>>>(x16, Wq16, bq, Q16, M, N, K);
  k_gemm_nt<1><<<(M / 128) * (N / 128), 256, 0, stream>>>(x16, Wk16, bk, K16, M, N, K);
  k_gemm_nt<1><<<(M / 128) * (N / 128), 256, 0, stream>>>(x16, Wv16, bv, V16, M, N, K);

  k_transpose_v<<<4096, 256, 0, stream>>>(V16, Vt16);

  k_scores_softmax<<<dim3(SEQL / 16, NH, BATCH), 256, 0, stream>>>(Q16, K16, mask, aw);

  k_attn_pv<<<dim3(SEQL / 64, NH, BATCH), 256, 0, stream>>>(aw, Vt16, att16);

  k_gemm_nt<0><<<(M / 128) * (N / 128), 256, 0, stream>>>(att16, Wo16, bo, out, M, N, K);
}

// Round 2
// 914.478 us; speedup vs baseline: 1.1413x; 1.1413x over previous
//
#include <hip/hip_runtime.h>
#include <stdint.h>

typedef _Float16 f16x8 __attribute__((ext_vector_type(8)));
typedef float    f32x4 __attribute__((ext_vector_type(4)));

// Problem constants
#define SEQL 1024
#define EMB  1024
#define NH   16
#define HD   64
#define BATCH 8
#define QKVN 3072   // fused QKV output width

// ---------------------------------------------------------------------------
// async global->LDS, 16B per lane (CK-style addrspace casts via uintptr_t)
// ---------------------------------------------------------------------------
__device__ __forceinline__ void gll16(const void* g, void* l) {
  __builtin_amdgcn_global_load_lds(
      (const __attribute__((address_space(1))) unsigned int*)(uintptr_t)g,
      (__attribute__((address_space(3))) unsigned int*)(uintptr_t)l, 16, 0, 0);
}

// ---------------------------------------------------------------------------
// One prep kernel: fp32->fp16 converts for x, Wq|Wk|Wv (stacked), Wo,
// plus bias concat bqkv = [bq; bk; bv].
// block ranges: [0,4096) x -> x16 ; [4096,4608) Wq ; [4608,5120) Wk ;
// [5120,5632) Wv ; [5632,6144) Wo ; [6144,6156) bias
// ---------------------------------------------------------------------------
__device__ __forceinline__ void cvt8(const float* __restrict__ in,
                                     _Float16* __restrict__ out, int i) {
  const float4* p = (const float4*)in;
  float4 a = p[2 * i], b = p[2 * i + 1];
  f16x8 o;
  o[0] = (_Float16)a.x; o[1] = (_Float16)a.y; o[2] = (_Float16)a.z; o[3] = (_Float16)a.w;
  o[4] = (_Float16)b.x; o[5] = (_Float16)b.y; o[6] = (_Float16)b.z; o[7] = (_Float16)b.w;
  ((f16x8*)out)[i] = o;
}

__global__ __launch_bounds__(256) void k_prep(const float* __restrict__ x,
                                              const float* __restrict__ Wq,
                                              const float* __restrict__ Wk,
                                              const float* __restrict__ Wv,
                                              const float* __restrict__ Wo,
                                              const float* __restrict__ bq,
                                              const float* __restrict__ bk,
                                              const float* __restrict__ bv,
                                              _Float16* __restrict__ x16,
                                              _Float16* __restrict__ Wqkv16,
                                              _Float16* __restrict__ Wo16,
                                              float* __restrict__ bqkv) {
  const int bid = blockIdx.x, tid = threadIdx.x;
  if (bid < 4096) {
    cvt8(x, x16, bid * 256 + tid);
  } else if (bid < 4608) {
    cvt8(Wq, Wqkv16, (bid - 4096) * 256 + tid);
  } else if (bid < 5120) {
    cvt8(Wk, Wqkv16 + (size_t)EMB * EMB, (bid - 4608) * 256 + tid);
  } else if (bid < 5632) {
    cvt8(Wv, Wqkv16 + (size_t)2 * EMB * EMB, (bid - 5120) * 256 + tid);
  } else if (bid < 6144) {
    cvt8(Wo, Wo16, (bid - 5632) * 256 + tid);
  } else {
    int i = (bid - 6144) * 256 + tid;  // 0..3071
    float v = (i < 1024) ? bq[i] : (i < 2048 ? bk[i - 1024] : bv[i - 2048]);
    bqkv[i] = v;
  }
}

// ---------------------------------------------------------------------------
// NT GEMM: C[M,N] = A[M,K] * B[N,K]^T + bias[N]
// 128x128 tile, BK=32, 4 waves (2x2 of 64x64), global_load_lds(16B) staging.
// LDS layout = lane-linear (addr = c*16B), exactly the global_load_lds order.
// ---------------------------------------------------------------------------
template <int OUT_F16>
__global__ __launch_bounds__(256) void k_gemm_nt(const _Float16* __restrict__ A,
                                                 const _Float16* __restrict__ B,
                                                 const float* __restrict__ bias,
                                                 void* __restrict__ Cv,
                                                 int M, int N, int K) {
  __shared__ __align__(16) _Float16 As[128 * 32];
  __shared__ __align__(16) _Float16 Bs[128 * 32];
  const int nb = N >> 7;
  const int bm = (int)blockIdx.x / nb, bn = (int)blockIdx.x % nb;
  const int m0 = bm << 7, n0 = bn << 7;
  const int tid = threadIdx.x;
  const int wave = tid >> 6, lane = tid & 63, quad = lane >> 4, l16 = lane & 15;
  const int wm = (wave & 1) << 6, wn = (wave >> 1) << 6;

  f32x4 acc[4][4] = {};

  const int c0 = tid, c1 = tid + 256;
  const int row0 = c0 >> 2, ko0 = (c0 & 3) << 3;
  const int row1 = c1 >> 2, ko1 = (c1 & 3) << 3;
  const _Float16* a0 = A + (size_t)(m0 + row0) * K + ko0;
  const _Float16* a1 = A + (size_t)(m0 + row1) * K + ko1;
  const _Float16* b0 = B + (size_t)(n0 + row0) * K + ko0;
  const _Float16* b1 = B + (size_t)(n0 + row1) * K + ko1;

  for (int k0 = 0; k0 < K; k0 += 32) {
    __syncthreads();
    gll16(a0 + k0, As + (size_t)c0 * 8);
    gll16(a1 + k0, As + (size_t)c1 * 8);
    gll16(b0 + k0, Bs + (size_t)c0 * 8);
    gll16(b1 + k0, Bs + (size_t)c1 * 8);
    __syncthreads();

    f16x8 af[4], bf[4];
#pragma unroll
    for (int i = 0; i < 4; ++i)
      af[i] = *(const f16x8*)(As + ((wm + (i << 4) + l16) << 5) + (quad << 3));
#pragma unroll
    for (int i = 0; i < 4; ++i)
      bf[i] = *(const f16x8*)(Bs + ((wn + (i << 4) + l16) << 5) + (quad << 3));
#pragma unroll
    for (int i = 0; i < 4; ++i)
#pragma unroll
      for (int j = 0; j < 4; ++j)
        acc[i][j] = __builtin_amdgcn_mfma_f32_16x16x32_f16(af[i], bf[j], acc[i][j], 0, 0, 0);
  }

#pragma unroll
  for (int j = 0; j < 4; ++j) {
    int col = n0 + wn + (j << 4) + l16;
    float bb = bias[col];
#pragma unroll
    for (int i = 0; i < 4; ++i) {
      int rowb = m0 + wm + (i << 4) + (quad << 2);
#pragma unroll
      for (int r = 0; r < 4; ++r) {
        float v = acc[i][j][r] + bb;
        if (OUT_F16)
          ((_Float16*)Cv)[(size_t)(rowb + r) * N + col] = (_Float16)v;
        else
          ((float*)Cv)[(size_t)(rowb + r) * N + col] = v;
      }
    }
  }
}

// ---------------------------------------------------------------------------
// V slice of QKV (b, s, 2048 + h*64+d, stride 3072) -> Vt (b, h, d, s) fp16
// ---------------------------------------------------------------------------
__global__ __launch_bounds__(256) void k_transpose_v(const _Float16* __restrict__ QKV,
                                                     _Float16* __restrict__ Vt) {
  int tid = blockIdx.x * 256 + threadIdx.x;  // 2^20 threads
  int d = tid & 63;
  int s0 = ((tid >> 6) & 127) << 3;
  int h = (tid >> 13) & 15;
  int b = tid >> 17;
  const _Float16* src = QKV + ((size_t)(b * SEQL + s0)) * QKVN + 2048 + h * HD + d;
  f16x8 t;
#pragma unroll
  for (int j = 0; j < 8; ++j) t[j] = src[(size_t)j * QKVN];
  *(f16x8*)(Vt + ((size_t)((b * NH + h) * HD + d)) * SEQL + s0) = t;
}

// ---------------------------------------------------------------------------
// Fused scores + softmax + aw-write + PV. Block = (qt, h, b): 16 Q rows.
// 4 waves x 256 K cols; score block in registers; normalized P round-trips
// through LDS (C-layout -> A-layout) for the PV MFMAs; cross-wave O reduce
// in LDS. Writes aw (fp32, mandatory output) and att16 (fp16).
// ---------------------------------------------------------------------------
#define PPAD 272  // 256 + 16 f16: row stride 136 words == 8 (mod 32) -> 4-way max
#define OPAD 68   // 64 + 4 f32: 2-way max (free)

__global__ __launch_bounds__(256) void k_attn_fused(const _Float16* __restrict__ QKV,
                                                    const _Float16* __restrict__ Vt,
                                                    const int* __restrict__ mask,
                                                    float* __restrict__ aw,
                                                    _Float16* __restrict__ att) {
  __shared__ __align__(16) _Float16 pbuf[4][16 * PPAD];  // 34816 B
  __shared__ float obuf[4][16 * OPAD];                   // 17408 B
  __shared__ float sm[4][16], sl[4][16];                 // 512 B

  const int qt = blockIdx.x, h = blockIdx.y, b = blockIdx.z;
  const int tid = threadIdx.x;
  const int wave = tid >> 6, lane = tid & 63, quad = lane >> 4, l16 = lane & 15;

  // ---- phase 1: scores (QK^T / sqrt(d), clip, mask) into registers --------
  const _Float16* Qbase =
      QKV + ((size_t)(b * SEQL + qt * 16 + l16)) * QKVN + h * HD + quad * 8;
  f16x8 qf0 = *(const f16x8*)(Qbase);
  f16x8 qf1 = *(const f16x8*)(Qbase + 32);

  float p[16][4];
  float mr[4], lr[4];
#pragma unroll
  for (int r = 0; r < 4; ++r) mr[r] = -3.0e38f;

  const int* mrow = mask + b * SEQL;
  const _Float16* Kb0 = QKV + (size_t)b * SEQL * QKVN + 1024 + h * HD + quad * 8;

#pragma unroll
  for (int ct = 0; ct < 16; ++ct) {
    int col = wave * 256 + ct * 16 + l16;
    const _Float16* Kb = Kb0 + (size_t)col * QKVN;
    f16x8 kf0 = *(const f16x8*)(Kb);
    f16x8 kf1 = *(const f16x8*)(Kb + 32);
    f32x4 acc = {};
    acc = __builtin_amdgcn_mfma_f32_16x16x32_f16(qf0, kf0, acc, 0, 0, 0);
    acc = __builtin_amdgcn_mfma_f32_16x16x32_f16(qf1, kf1, acc, 0, 0, 0);
    bool mk = (mrow[col] == 0);
#pragma unroll
    for (int r = 0; r < 4; ++r) {
      float s = acc[r] * 0.125f;          // 1/sqrt(64)
      s = fminf(fmaxf(s, -50.f), 50.f);   // clip BEFORE mask (matches ref)
      if (mk) s = -1.0e9f;
      p[ct][r] = s;
      mr[r] = fmaxf(mr[r], s);
    }
  }

  // ---- phase 2: softmax stats ---------------------------------------------
#pragma unroll
  for (int r = 0; r < 4; ++r) {
    float m = mr[r];
    m = fmaxf(m, __shfl_xor(m, 1, 16));
    m = fmaxf(m, __shfl_xor(m, 2, 16));
    m = fmaxf(m, __shfl_xor(m, 4, 16));
    m = fmaxf(m, __shfl_xor(m, 8, 16));
    mr[r] = m;
  }
#pragma unroll
  for (int r = 0; r < 4; ++r) lr[r] = 0.f;
#pragma unroll
  for (int ct = 0; ct < 16; ++ct) {
#pragma unroll
    for (int r = 0; r < 4; ++r) {
      float e = __expf(p[ct][r] - mr[r]);
      p[ct][r] = e;
      lr[r] += e;
    }
  }
#pragma unroll
  for (int r = 0; r < 4; ++r) {
    float l = lr[r];
    l += __shfl_xor(l, 1, 16);
    l += __shfl_xor(l, 2, 16);
    l += __shfl_xor(l, 4, 16);
    l += __shfl_xor(l, 8, 16);
    lr[r] = l;
  }
  if (l16 == 0) {
#pragma unroll
    for (int r = 0; r < 4; ++r) {
      sm[wave][quad * 4 + r] = mr[r];
      sl[wave][quad * 4 + r] = lr[r];
    }
  }
  __syncthreads();

  float f[4];
#pragma unroll
  for (int r = 0; r < 4; ++r) {
    int row = quad * 4 + r;
    float M = fmaxf(fmaxf(sm[0][row], sm[1][row]), fmaxf(sm[2][row], sm[3][row]));
    float L = sl[0][row] * __expf(sm[0][row] - M) + sl[1][row] * __expf(sm[1][row] - M) +
              sl[2][row] * __expf(sm[2][row] - M) + sl[3][row] * __expf(sm[3][row] - M);
    f[r] = __expf(mr[r] - M) / L;
  }

  // ---- phase 3: write aw (fp32 global) + P (fp16, wave-private LDS) -------
  float* awb = aw + (((size_t)(b * NH + h)) * SEQL + qt * 16) * SEQL;
  _Float16* pw = pbuf[wave];
#pragma unroll
  for (int ct = 0; ct < 16; ++ct) {
#pragma unroll
    for (int r = 0; r < 4; ++r) {
      float v = p[ct][r] * f[r];
      awb[(size_t)(quad * 4 + r) * SEQL + wave * 256 + ct * 16 + l16] = v;
      pw[(quad * 4 + r) * PPAD + ct * 16 + l16] = (_Float16)v;
    }
  }

  // ---- phase 4: PV over this wave's 256-col k-slice -----------------------
  f32x4 opv[4] = {};
  const _Float16* vtb =
      Vt + ((size_t)(b * NH + h)) * HD * SEQL + wave * 256 + quad * 8;
#pragma unroll
  for (int k = 0; k < 256; k += 32) {
    f16x8 af = *(const f16x8*)(pw + l16 * PPAD + k + quad * 8);
#pragma unroll
    for (int nt = 0; nt < 4; ++nt) {
      f16x8 bf = *(const f16x8*)(vtb + (size_t)(nt * 16 + l16) * SEQL + k);
      opv[nt] = __builtin_amdgcn_mfma_f32_16x16x32_f16(af, bf, opv[nt], 0, 0, 0);
    }
  }

  // ---- phase 5: cross-wave O reduction + att write ------------------------
#pragma unroll
  for (int nt = 0; nt < 4; ++nt)
#pragma unroll
    for (int r = 0; r < 4; ++r)
      obuf[wave][(quad * 4 + r) * OPAD + nt * 16 + l16] = opv[nt][r];
  __syncthreads();

  {
    int col = tid & 63;
    int r0 = tid >> 6;
#pragma unroll
    for (int i = 0; i < 4; ++i) {
      int row = r0 + i * 4;
      float o = obuf[0][row * OPAD + col] + obuf[1][row * OPAD + col] +
                obuf[2][row * OPAD + col] + obuf[3][row * OPAD + col];
      att[((size_t)(b * SEQL + qt * 16 + row)) * EMB + h * HD + col] = (_Float16)o;
    }
  }
}

// ---------------------------------------------------------------------------
// launch
// ---------------------------------------------------------------------------
extern "C" void kernel_launch(void* const* d_in, const int* in_sizes, int n_in,
                              void* d_out, int out_size, void* d_ws, size_t ws_size,
                              hipStream_t stream) {
  const float* x  = (const float*)d_in[0];
  const int* mask = (const int*)d_in[1];
  const float* Wq = (const float*)d_in[2];
  const float* bq = (const float*)d_in[3];
  const float* Wk = (const float*)d_in[4];
  const float* bk = (const float*)d_in[5];
  const float* Wv = (const float*)d_in[6];
  const float* bv = (const float*)d_in[7];
  const float* Wo = (const float*)d_in[8];
  const float* bo = (const float*)d_in[9];

  float* out = (float*)d_out;
  float* aw = out + (size_t)BATCH * SEQL * EMB;  // 8,388,608 floats in

  char* ws = (char*)d_ws;
  _Float16* x16    = (_Float16*)(ws);                        // 16 MB
  _Float16* Wqkv16 = (_Float16*)(ws + ((size_t)16 << 20));   // 6 MB
  _Float16* Wo16   = (_Float16*)(ws + ((size_t)22 << 20));   // 2 MB
  float*    bqkv   = (float*)   (ws + ((size_t)24 << 20));   // 12 KB
  _Float16* QKV16  = (_Float16*)(ws + ((size_t)25 << 20));   // 48 MB
  _Float16* Vt16   = (_Float16*)(ws + ((size_t)73 << 20));   // 16 MB
  _Float16* att16  = (_Float16*)(ws + ((size_t)89 << 20));   // 16 MB (total 105 MB)

  const int M = BATCH * SEQL;

  k_prep<<<6156, 256, 0, stream>>>(x, Wq, Wk, Wv, Wo, bq, bk, bv,
                                   x16, Wqkv16, Wo16, bqkv);

  k_gemm_nt<1><<<(M / 128) * (QKVN / 128), 256, 0, stream>>>(x16, Wqkv16, bqkv, QKV16,
                                                             M, QKVN, EMB);

  k_transpose_v<<<4096, 256, 0, stream>>>(QKV16, Vt16);

  k_attn_fused<<<dim3(SEQL / 16, NH, BATCH), 256, 0, stream>>>(QKV16, Vt16, mask, aw, att16);

  k_gemm_nt<0><<<(M / 128) * (EMB / 128), 256, 0, stream>>>(att16, Wo16, bo, out,
                                                            M, EMB, EMB);
}